// Round 14
// baseline (1130.231 us; speedup 1.0000x reference)
//
#include <hip/hip_runtime.h>
#include <hip/hip_bf16.h>

// Problem constants
#define NB     32
#define CDIM   256
#define HWDIM  1024          // 32*32
#define NROWS  32768         // NB*HWDIM
#define NE     8192
#define PANELS 4
#define COLS_PER_PANEL 2048
#define NT_PER_PANEL   16    // 2048/128
#define CAND_CAP 64

typedef float f32x4 __attribute__((ext_vector_type(4)));
typedef short bf16x8 __attribute__((ext_vector_type(8)));

// d_out layout (floats): z_q_out | loss | d | indices
#define OUT_ZQ   0ull
#define OUT_LOSS 8388608ull
#define OUT_D    8388609ull
#define OUT_IDX  276824065ull   // 8388609 + 32768*8192

// workspace layout (bytes)
#define WS_ZF    0ull           // [NROWS][256] bf16 (16 MB)
#define WS_EMB   16777216ull    // [NE][256] bf16 (4 MB)
#define WS_ASUM  20971520ull    // [NROWS] f32 (np-pairwise-exact)
#define WS_BSUM  21102592ull    // [NE] f32
#define WS_PMINV 21135360ull    // [PANELS][NROWS] u32 panel min d-bits (512 KB)
#define WS_GMIN  21659648ull    // [NROWS] u32 final min d-bits
#define WS_CNT   21790720ull    // [NROWS] i32 candidate counts
#define WS_IDX   21921792ull    // [NROWS] i32
#define WS_LOSS  22052864ull    // f32 accumulator
// candidate lists live in the (not-yet-written) z_q output region: 16.8 MB < 33 MB

#define REFINE_DELTA 2.5e-4f

typedef __attribute__((address_space(1))) const void global_cvoid;
typedef __attribute__((address_space(3))) void lds_void;

__device__ __forceinline__ void gl_lds16(const void* g, void* l) {
  __builtin_amdgcn_global_load_lds((global_cvoid*)g, (lds_void*)l, 16, 0, 0);
}

// ---- prep: transpose z[b][c][hw] -> zf[n][c] (bf16), n = b*1024 + hw ----
__global__ void k_prep_zf(const float* __restrict__ z, __hip_bfloat16* __restrict__ zf) {
  __shared__ float tile[32][33];
  const int b   = blockIdx.z;
  const int c0  = blockIdx.y * 32;
  const int hw0 = blockIdx.x * 32;
  const int tx  = threadIdx.x & 31;
  const int ty  = threadIdx.x >> 5;   // 0..7
  const float* zb = z + (size_t)b * (CDIM * HWDIM);
#pragma unroll
  for (int i = 0; i < 4; ++i) {
    int c = ty + i * 8;
    tile[c][tx] = zb[(size_t)(c0 + c) * HWDIM + hw0 + tx];
  }
  __syncthreads();
#pragma unroll
  for (int i = 0; i < 4; ++i) {
    int row = ty + i * 8;                 // hw-local
    int n = b * HWDIM + hw0 + row;
    zf[(size_t)n * CDIM + c0 + tx] = __float2bfloat16(tile[tx][row]);
  }
}

// ---- prep: A[n] = np.sum(zf*zf, axis=1) BIT-EXACT numpy pairwise f32 ----
__global__ void k_prep_asum(const float* __restrict__ z, float* __restrict__ asum) {
#pragma clang fp contract(off)
  const int t   = threadIdx.x;
  const int blk = blockIdx.x;           // 0..127
  const int b   = blk >> 2;
  const int hw0 = (blk & 3) * 256;
  const float* zb = z + (size_t)b * (CDIM * HWDIM) + hw0 + t;
  float half[2];
#pragma unroll
  for (int h = 0; h < 2; ++h) {
    float r[8];
#pragma unroll
    for (int j = 0; j < 8; ++j) {
      const float v = zb[(size_t)(h * 128 + j) * HWDIM];
      r[j] = v * v;
    }
    for (int i = 1; i < 16; ++i) {
#pragma unroll
      for (int j = 0; j < 8; ++j) {
        const float v = zb[(size_t)(h * 128 + i * 8 + j) * HWDIM];
        r[j] += v * v;
      }
    }
    half[h] = ((r[0] + r[1]) + (r[2] + r[3])) + ((r[4] + r[5]) + (r[6] + r[7]));
  }
  asum[b * HWDIM + hw0 + t] = half[0] + half[1];
}

// ---- prep: emb -> bf16, B[e] = sum_c e^2 (fp32) ----
__global__ void k_prep_emb(const float* __restrict__ emb, __hip_bfloat16* __restrict__ embb,
                           float* __restrict__ bsum) {
  const int t = threadIdx.x, lane = t & 63, w = t >> 6;
  const int row = blockIdx.x * 4 + w;
  const float4 v = ((const float4*)(emb + (size_t)row * CDIM))[lane];
  __hip_bfloat16* dst = embb + (size_t)row * CDIM + lane * 4;
  dst[0] = __float2bfloat16(v.x);
  dst[1] = __float2bfloat16(v.y);
  dst[2] = __float2bfloat16(v.z);
  dst[3] = __float2bfloat16(v.w);
  float s = v.x * v.x + v.y * v.y + v.z * v.z + v.w * v.w;
#pragma unroll
  for (int m = 32; m; m >>= 1) s += __shfl_xor(s, m, 64);
  if (lane == 0) bsum[row] = s;
}

// ---- GEMM + d-write + panel-local running min + candidate collection ----
// R14: production = R8 EXACT (the 745us best). Additionally a full-grid
// ablation probe k_gemm_t<1>: identical code/barriers, but the d-store and
// candidate atomics are replaced by asm-volatile value sinks (rule #17).
// Probe writes only pminv, which production overwrites identically ->
// deterministic. Pre-registered read: probe 150-350us => stores are the
// wall (R15: LDS-buffered row-streamed writeout); 550-745us => staging/
// barrier latency is the wall (R15: pipeline restructure).
template <int V>
__global__ __launch_bounds__(256) void k_gemm_t(
    const __hip_bfloat16* __restrict__ zf, const __hip_bfloat16* __restrict__ embb,
    const float* __restrict__ asum, const float* __restrict__ bsum,
    float* __restrict__ dmat,
    unsigned* __restrict__ pminv, int* __restrict__ cnt,
    unsigned long long* __restrict__ cand) {
  __shared__ __hip_bfloat16 As[128 * 64];
  __shared__ __hip_bfloat16 Bs[128 * 64];
  __shared__ unsigned rowMin[128];

  const int tid = threadIdx.x;
  const int lane = tid & 63;
  const int w = tid >> 6;
  const int wr = w >> 1, wc = w & 1;
  const int l15 = lane & 15, g = lane >> 4;
  const int sw = l15 & 7;                 // read-side XOR swizzle key
  // XCD swizzle: lin = bx + 256*by; xcd = lin%8 gets 128 consecutive slots
  const int lin = blockIdx.x + (blockIdx.y << 8);
  const int swzb = (lin & 7) * 128 + (lin >> 3);
  const int bx = swzb & 255, by = swzb >> 8;
  const int row0 = bx * 128;
  const int colp = by * COLS_PER_PANEL;

  if (tid < 128) rowMin[tid] = 0x7f800000u;

  float av[4][4];
#pragma unroll
  for (int m = 0; m < 4; ++m) {
    const f32x4 a4 = *(const f32x4*)(asum + row0 + wr * 64 + m * 16 + g * 4);
#pragma unroll
    for (int r = 0; r < 4; ++r) av[m][r] = a4[r];
  }

  for (int nt = 0; nt < NT_PER_PANEL; ++nt) {
    const int col0 = colp + nt * 128;
    f32x4 acc[4][4];
#pragma unroll
    for (int m = 0; m < 4; ++m)
#pragma unroll
      for (int n = 0; n < 4; ++n) acc[m][n] = (f32x4){0.f, 0.f, 0.f, 0.f};

    float bv[4];
#pragma unroll
    for (int n = 0; n < 4; ++n) bv[n] = bsum[col0 + wc * 64 + n * 16 + l15];

    for (int ks = 0; ks < 4; ++ks) {
      const int k0 = ks * 64;
#pragma unroll
      for (int I = 0; I < 4; ++I) {
        const int boff = I * 4096 + tid * 16;
        const int r   = boff >> 7;          // 128 B per row
        const int ch  = (boff >> 4) & 7;    // physical 16B chunk in row
        const int chs = ch ^ (r & 7);       // logical chunk at this slot
        gl_lds16((const char*)zf   + (size_t)(row0 + r) * 512 + k0 * 2 + chs * 16,
                 (char*)As + boff);
        gl_lds16((const char*)embb + (size_t)(col0 + r) * 512 + k0 * 2 + chs * 16,
                 (char*)Bs + boff);
      }
      __syncthreads();
#pragma unroll
      for (int kk = 0; kk < 2; ++kk) {
        bf16x8 af[4], bfr[4];
#pragma unroll
        for (int m = 0; m < 4; ++m)
          af[m] = *(const bf16x8*)((const char*)As +
                    (wr * 64 + m * 16 + l15) * 128 + (((kk << 2) | g) ^ sw) * 16);
#pragma unroll
        for (int n = 0; n < 4; ++n)
          bfr[n] = *(const bf16x8*)((const char*)Bs +
                    (wc * 64 + n * 16 + l15) * 128 + (((kk << 2) | g) ^ sw) * 16);
#pragma unroll
        for (int m = 0; m < 4; ++m)
#pragma unroll
          for (int n = 0; n < 4; ++n)
            acc[m][n] = __builtin_amdgcn_mfma_f32_16x16x32_bf16(af[m], bfr[n], acc[m][n], 0, 0, 0);
      }
      __syncthreads();
    }

    // pass 1: d = A - 2C, store (or sink), merge per-row running min
#pragma unroll
    for (int m = 0; m < 4; ++m) {
#pragma unroll
      for (int r = 0; r < 4; ++r) {
        const int rowL = wr * 64 + m * 16 + g * 4 + r;
        const size_t rowbase = (size_t)(row0 + rowL) * NE;
        unsigned mn = 0x7f800000u;
#pragma unroll
        for (int n = 0; n < 4; ++n) {
          const int col = col0 + wc * 64 + n * 16 + l15;
          const float dv = fmaf(-2.f, acc[m][n][r], av[m][r] + bv[n]);
          if (V == 0) {
            __builtin_nontemporal_store(dv, &dmat[rowbase + col]);
          } else {
            asm volatile("" :: "v"(dv));   // keep live, no store
          }
          const unsigned bb = __float_as_uint(dv);   // d > 0: bit order == value order
          mn = bb < mn ? bb : mn;
        }
#pragma unroll
        for (int s = 1; s < 16; s <<= 1) {
          const unsigned o = __shfl_xor(mn, s, 64);
          mn = o < mn ? o : mn;
        }
        if (l15 == 0) atomicMin(&rowMin[rowL], mn);
      }
    }
    __syncthreads();
    // pass 2: collect candidates within running_min + delta
#pragma unroll
    for (int m = 0; m < 4; ++m) {
#pragma unroll
      for (int r = 0; r < 4; ++r) {
        const int rowL = wr * 64 + m * 16 + g * 4 + r;
        const float th = __uint_as_float(rowMin[rowL]) + REFINE_DELTA;
#pragma unroll
        for (int n = 0; n < 4; ++n) {
          const int col = col0 + wc * 64 + n * 16 + l15;
          const float dv = fmaf(-2.f, acc[m][n][r], av[m][r] + bv[n]);
          const bool hit = dv <= th;
          if (V == 0) {
            if (hit) {
              const int p = atomicAdd(&cnt[row0 + rowL], 1);
              if (p < CAND_CAP)
                cand[(size_t)(row0 + rowL) * CAND_CAP + p] =
                    ((unsigned long long)__float_as_uint(dv) << 32) | (unsigned)col;
            }
          } else {
            asm volatile("" :: "v"((int)hit), "v"(dv));  // keep predicate+value live
          }
        }
      }
    }
  }
  if (tid < 128) pminv[(size_t)by * NROWS + row0 + tid] = rowMin[tid];
}

// ---- combine panel minima -> final per-row min d value (bits) ----
__global__ void k_combine_dmin(const unsigned* __restrict__ pminv,
                               unsigned* __restrict__ gmin) {
  const int n = blockIdx.x * 256 + threadIdx.x;
  unsigned k = pminv[n];
#pragma unroll
  for (int p = 1; p < PANELS; ++p) {
    const unsigned o = pminv[(size_t)p * NROWS + n];
    k = o < k ? o : k;
  }
  gmin[n] = k;
}

// ---- exact np-replication argmin over collected candidates ----
__global__ __launch_bounds__(256) void k_exact(
    const float* __restrict__ dmat, const unsigned* __restrict__ gmin,
    const int* __restrict__ cnt, const unsigned long long* __restrict__ cand,
    const float* __restrict__ z, const float* __restrict__ emb,
    const float* __restrict__ asum,
    float* __restrict__ out_idx, int* __restrict__ idx_i) {
  __shared__ float zrow[4][CDIM];
  const int w = threadIdx.x >> 6, lane = threadIdx.x & 63;
  const int n = blockIdx.x * 4 + w;
  const int b = n >> 10, hw = n & 1023;

  const float* zb = z + (size_t)b * (CDIM * HWDIM) + hw;
#pragma unroll
  for (int j = 0; j < 4; ++j)
    zrow[w][lane * 4 + j] = zb[(size_t)(lane * 4 + j) * HWDIM];
  __syncthreads();

  const float A = asum[n];
  const float th = __uint_as_float(gmin[n]) + REFINE_DELTA;
  const float* zr = &zrow[w][lane * 4];
  const int c_ = cnt[n];
  unsigned long long best = ~0ull;

  if (c_ <= CAND_CAP) {
    for (int i = 0; i < c_; ++i) {
      const unsigned long long e = cand[(size_t)n * CAND_CAP + i];
      if (__uint_as_float((unsigned)(e >> 32)) > th) continue;  // vs FINAL min
      const int col = (int)(unsigned)(e & 0xffffffffull);
      const float4 ev = ((const float4*)(emb + (size_t)col * CDIM))[lane];
      double acc = (double)zr[0] * (double)ev.x;
      acc = fma((double)zr[1], (double)ev.y, acc);
      acc = fma((double)zr[2], (double)ev.z, acc);
      acc = fma((double)zr[3], (double)ev.w, acc);
#pragma unroll
      for (int s = 1; s < 64; s <<= 1) acc += __shfl_xor(acc, s, 64);
      const float C32 = (float)acc;
      const float D = A - 2.0f * C32;            // np: fl(A - 2C); 2C exact
      const unsigned long long key =
          ((unsigned long long)__float_as_uint(D) << 32) | (unsigned)col;
      if (key < best) best = key;
    }
  } else {
    // overflow fallback (rare): full row scan of stored d
    const float* drow = dmat + (size_t)n * NE;
    for (int i = 0; i < NE / 64; ++i) {
      const int colbase = i * 64;
      const float v = drow[colbase + lane];
      unsigned long long mask = __ballot(v <= th);
      while (mask) {
        const int bpos = (int)__builtin_ctzll(mask);
        mask &= mask - 1;
        const int col = colbase + bpos;
        const float4 ev = ((const float4*)(emb + (size_t)col * CDIM))[lane];
        double acc = (double)zr[0] * (double)ev.x;
        acc = fma((double)zr[1], (double)ev.y, acc);
        acc = fma((double)zr[2], (double)ev.z, acc);
        acc = fma((double)zr[3], (double)ev.w, acc);
#pragma unroll
        for (int s = 1; s < 64; s <<= 1) acc += __shfl_xor(acc, s, 64);
        const float C32 = (float)acc;
        const float D = A - 2.0f * C32;
        const unsigned long long key =
            ((unsigned long long)__float_as_uint(D) << 32) | (unsigned)col;
        if (key < best) best = key;
      }
    }
  }
  if (lane == 0) {
    const int bi = (int)(unsigned)(best & 0xffffffffull);
    idx_i[n] = bi;
    out_idx[n] = (float)bi;
  }
}

// ---- gather z_q, straight-through output, loss partial ----
__global__ void k_gather(const float* __restrict__ z, const float* __restrict__ emb,
                         const int* __restrict__ idx_i, float* __restrict__ zq_out,
                         float* __restrict__ loss_acc) {
  float part = 0.f;
  const unsigned stride = gridDim.x * 256u;
  for (unsigned i = blockIdx.x * 256u + threadIdx.x; i < 8388608u; i += stride) {
    const int hw = i & 1023;
    const int c  = (i >> 10) & 255;
    const int b  = i >> 18;
    const int n  = b * HWDIM + hw;
    const int e  = idx_i[n];
    const float zq = emb[(size_t)e * CDIM + c];
    const float zv = z[i];
    __builtin_nontemporal_store(zv + (zq - zv), &zq_out[i]);  // straight-through
    const float df = zq - zv;
    part = fmaf(df, df, part);
  }
#pragma unroll
  for (int s = 32; s; s >>= 1) part += __shfl_xor(part, s, 64);
  __shared__ float wsum[4];
  if ((threadIdx.x & 63) == 0) wsum[threadIdx.x >> 6] = part;
  __syncthreads();
  if (threadIdx.x == 0) atomicAdd(loss_acc, wsum[0] + wsum[1] + wsum[2] + wsum[3]);
}

__global__ void k_loss_final(const float* __restrict__ loss_acc, float* __restrict__ out_loss) {
  const float m = *loss_acc / 8388608.0f;
  *out_loss = m + 0.25f * m;
}

extern "C" void kernel_launch(void* const* d_in, const int* in_sizes, int n_in,
                              void* d_out, int out_size, void* d_ws, size_t ws_size,
                              hipStream_t stream) {
  const float* z   = (const float*)d_in[0];
  const float* emb = (const float*)d_in[1];
  float* out = (float*)d_out;
  char* ws = (char*)d_ws;

  __hip_bfloat16* zf   = (__hip_bfloat16*)(ws + WS_ZF);
  __hip_bfloat16* embb = (__hip_bfloat16*)(ws + WS_EMB);
  float* asum = (float*)(ws + WS_ASUM);
  float* bsum = (float*)(ws + WS_BSUM);
  unsigned* pminv = (unsigned*)(ws + WS_PMINV);
  unsigned* gmin = (unsigned*)(ws + WS_GMIN);
  int* cntp = (int*)(ws + WS_CNT);
  int* idxi = (int*)(ws + WS_IDX);
  float* lossacc = (float*)(ws + WS_LOSS);
  // candidate lists borrow the z_q output region (rewritten later by k_gather)
  unsigned long long* cand = (unsigned long long*)(out + OUT_ZQ);

  (void)hipMemsetAsync(ws + WS_CNT, 0, NROWS * 4, stream);
  (void)hipMemsetAsync(ws + WS_LOSS, 0, 4, stream);

  k_prep_zf<<<dim3(32, 8, 32), 256, 0, stream>>>(z, zf);
  k_prep_asum<<<128, 256, 0, stream>>>(z, asum);
  k_prep_emb<<<2048, 256, 0, stream>>>(emb, embb, bsum);
  // ABLATION PROBE (V=1): no global stores from epilogue; timing-only.
  // Writes pminv, which the production dispatch overwrites identically.
  k_gemm_t<1><<<dim3(256, PANELS), 256, 0, stream>>>(zf, embb, asum, bsum,
                                                     out + OUT_D, pminv, cntp, cand);
  // PRODUCTION (V=0): real d / pminv / cnt / cand.
  k_gemm_t<0><<<dim3(256, PANELS), 256, 0, stream>>>(zf, embb, asum, bsum,
                                                     out + OUT_D, pminv, cntp, cand);
  k_combine_dmin<<<128, 256, 0, stream>>>(pminv, gmin);
  k_exact<<<8192, 256, 0, stream>>>(out + OUT_D, gmin, cntp, cand, z, emb, asum,
                                    out + OUT_IDX, idxi);
  k_gather<<<2048, 256, 0, stream>>>(z, emb, idxi, out + OUT_ZQ, lossacc);
  k_loss_final<<<1, 1, 0, stream>>>(lossacc, out + OUT_LOSS);
}

// Round 15
// 776.172 us; speedup vs baseline: 1.4562x; 1.4562x over previous
//
#include <hip/hip_runtime.h>
#include <hip/hip_bf16.h>

// Problem constants
#define NB     32
#define CDIM   256
#define HWDIM  1024          // 32*32
#define NROWS  32768         // NB*HWDIM
#define NE     8192
#define ROWS   32            // z-rows per block
#define COLSB  1024          // emb-cols per block
#define NTIL   8             // 128-col B-tiles per block
#define NPAN   8             // col-groups (panels)
#define CAND_CAP 64

typedef float f32x4 __attribute__((ext_vector_type(4)));
typedef short bf16x8 __attribute__((ext_vector_type(8)));

// d_out layout (floats): z_q_out | loss | d | indices
#define OUT_ZQ   0ull
#define OUT_LOSS 8388608ull
#define OUT_D    8388609ull
#define OUT_IDX  276824065ull   // 8388609 + 32768*8192

// workspace layout (bytes)
#define WS_ZF    0ull           // [NROWS][256] bf16 (16 MB)
#define WS_EMB   16777216ull    // [NE][256] bf16 (4 MB)
#define WS_ASUM  20971520ull    // [NROWS] f32 (np-pairwise-exact)
#define WS_BSUM  21102592ull    // [NE] f32
#define WS_PMINV 21135360ull    // [NPAN][NROWS] u32 panel min d-bits (1 MB)
#define WS_GMIN  22183936ull    // [NROWS] u32 final min d-bits
#define WS_CNT   22315008ull    // [NROWS] i32 candidate counts
#define WS_IDX   22446080ull    // [NROWS] i32
#define WS_LOSS  22577152ull    // f32 accumulator
// candidate lists live in the (not-yet-written) z_q output region: 16.8 MB < 33 MB

#define REFINE_DELTA 2.5e-4f

typedef __attribute__((address_space(1))) const void global_cvoid;
typedef __attribute__((address_space(3))) void lds_void;

__device__ __forceinline__ void gl_lds16(const void* g, void* l) {
  __builtin_amdgcn_global_load_lds((global_cvoid*)g, (lds_void*)l, 16, 0, 0);
}

// ---- prep: transpose z[b][c][hw] -> zf[n][c] (bf16), n = b*1024 + hw ----
__global__ void k_prep_zf(const float* __restrict__ z, __hip_bfloat16* __restrict__ zf) {
  __shared__ float tile[32][33];
  const int b   = blockIdx.z;
  const int c0  = blockIdx.y * 32;
  const int hw0 = blockIdx.x * 32;
  const int tx  = threadIdx.x & 31;
  const int ty  = threadIdx.x >> 5;   // 0..7
  const float* zb = z + (size_t)b * (CDIM * HWDIM);
#pragma unroll
  for (int i = 0; i < 4; ++i) {
    int c = ty + i * 8;
    tile[c][tx] = zb[(size_t)(c0 + c) * HWDIM + hw0 + tx];
  }
  __syncthreads();
#pragma unroll
  for (int i = 0; i < 4; ++i) {
    int row = ty + i * 8;                 // hw-local
    int n = b * HWDIM + hw0 + row;
    zf[(size_t)n * CDIM + c0 + tx] = __float2bfloat16(tile[tx][row]);
  }
}

// ---- prep: A[n] = np.sum(zf*zf, axis=1) BIT-EXACT numpy pairwise f32 ----
__global__ void k_prep_asum(const float* __restrict__ z, float* __restrict__ asum) {
#pragma clang fp contract(off)
  const int t   = threadIdx.x;
  const int blk = blockIdx.x;           // 0..127
  const int b   = blk >> 2;
  const int hw0 = (blk & 3) * 256;
  const float* zb = z + (size_t)b * (CDIM * HWDIM) + hw0 + t;
  float half[2];
#pragma unroll
  for (int h = 0; h < 2; ++h) {
    float r[8];
#pragma unroll
    for (int j = 0; j < 8; ++j) {
      const float v = zb[(size_t)(h * 128 + j) * HWDIM];
      r[j] = v * v;
    }
    for (int i = 1; i < 16; ++i) {
#pragma unroll
      for (int j = 0; j < 8; ++j) {
        const float v = zb[(size_t)(h * 128 + i * 8 + j) * HWDIM];
        r[j] += v * v;
      }
    }
    half[h] = ((r[0] + r[1]) + (r[2] + r[3])) + ((r[4] + r[5]) + (r[6] + r[7]));
  }
  asum[b * HWDIM + hw0 + t] = half[0] + half[1];
}

// ---- prep: emb -> bf16, B[e] = sum_c e^2 (fp32) ----
__global__ void k_prep_emb(const float* __restrict__ emb, __hip_bfloat16* __restrict__ embb,
                           float* __restrict__ bsum) {
  const int t = threadIdx.x, lane = t & 63, w = t >> 6;
  const int row = blockIdx.x * 4 + w;
  const float4 v = ((const float4*)(emb + (size_t)row * CDIM))[lane];
  __hip_bfloat16* dst = embb + (size_t)row * CDIM + lane * 4;
  dst[0] = __float2bfloat16(v.x);
  dst[1] = __float2bfloat16(v.y);
  dst[2] = __float2bfloat16(v.z);
  dst[3] = __float2bfloat16(v.w);
  float s = v.x * v.x + v.y * v.y + v.z * v.z + v.w * v.w;
#pragma unroll
  for (int m = 32; m; m >>= 1) s += __shfl_xor(s, m, 64);
  if (lane == 0) bsum[row] = s;
}

// ---- GEMM + d-write (LDS-staged sequential writeout) + candidates ----
// R15: R14's ablation proved stores cost ~500us of 745 (2.1 TB/s effective
// vs fillBuffer's 6.5) -- sub-KB scattered NT writes at 32KB row stride are
// the wall; chunk size 64B->256B was null, so the fix is MULTI-KB runs.
// Block = 32 rows x 1024 cols: A-stripe staged once (16KB); 8 B-tiles
// (128x256, R8-proven swizzled layout); swapped-operand MFMA (R11/R12-
// verified via indices output) accumulates the whole panel in registers
// (acc 2x8 f32x4 = 64 VGPR); then two 16-row phases dump dv into the
// REUSED Bs buffer (64KB, XOR-swizzled) and each wave streams 4KB
// sequential runs per d-row (1KB/instruction).
__global__ __launch_bounds__(512) void k_gemm(
    const __hip_bfloat16* __restrict__ zf, const __hip_bfloat16* __restrict__ embb,
    const float* __restrict__ asum, const float* __restrict__ bsum,
    float* __restrict__ dmat,
    unsigned* __restrict__ pminv, int* __restrict__ cnt,
    unsigned long long* __restrict__ cand) {
  __shared__ __hip_bfloat16 As[ROWS * 256];   // 16 KB
  __shared__ __hip_bfloat16 Bs[128 * 256];    // 64 KB; reused as d dump buffer
  __shared__ unsigned rowMin32[ROWS];

  const int tid = threadIdx.x;                // 0..511
  const int lane = tid & 63;
  const int w = tid >> 6;                     // 0..7 (wave = 16-col slice)
  const int l15 = lane & 15, g = lane >> 4;
  // XCD swizzle: each XCD owns one col-group; bx sequential within
  const int lin = blockIdx.x + (blockIdx.y << 10);
  const int v = (lin & 7) * 1024 + (lin >> 3);
  const int bx = v & 1023, by = v >> 10;
  const int row0 = bx * ROWS;
  const int col0 = by * COLSB;

  if (tid < ROWS) rowMin32[tid] = 0x7f800000u;

  // stage A-stripe once: [32 rows][512B], 16B-chunk-swizzled (chs = ch^(r&7))
#pragma unroll
  for (int I = 0; I < 2; ++I) {
    const int boff = I * 8192 + tid * 16;
    const int r   = boff >> 9;
    const int ch  = (boff >> 4) & 31;
    const int chs = ch ^ (r & 7);
    gl_lds16((const char*)zf + (size_t)(row0 + r) * 512 + chs * 16,
             (char*)As + boff);
  }
  auto STAGE_B = [&](int nt) {
#pragma unroll
    for (int I = 0; I < 8; ++I) {
      const int boff = I * 8192 + tid * 16;
      const int r   = boff >> 9;
      const int ch  = (boff >> 4) & 31;
      const int chs = ch ^ (r & 7);
      gl_lds16((const char*)embb + (size_t)(col0 + nt * 128 + r) * 512 + chs * 16,
               (char*)Bs + boff);
    }
  };

  f32x4 acc[2][NTIL];
#pragma unroll
  for (int m = 0; m < 2; ++m)
#pragma unroll
    for (int nt = 0; nt < NTIL; ++nt) acc[m][nt] = (f32x4){0.f, 0.f, 0.f, 0.f};

  STAGE_B(0);
  __syncthreads();
#pragma unroll
  for (int nt = 0; nt < NTIL; ++nt) {
#pragma unroll
    for (int kk = 0; kk < 8; ++kk) {
      const int kc = ((kk << 2) | g) ^ (l15 & 7);   // swizzled 16B chunk
      const bf16x8 bfr = *(const bf16x8*)((const char*)Bs +
                           (w * 16 + l15) * 512 + kc * 16);
#pragma unroll
      for (int m = 0; m < 2; ++m) {
        const bf16x8 af = *(const bf16x8*)((const char*)As +
                            (m * 16 + l15) * 512 + kc * 16);
        // swapped operands: D-row = af's l15 (z-row), D-col = bfr tile col
        acc[m][nt] = __builtin_amdgcn_mfma_f32_16x16x32_bf16(bfr, af, acc[m][nt], 0, 0, 0);
      }
    }
    __syncthreads();              // all waves done reading Bs(nt)
    if (nt + 1 < NTIL) STAGE_B(nt + 1);
    __syncthreads();              // Bs(nt+1) staged & visible
  }

  // pass 1: per-row running min over this block's 1024 cols
  const float av0 = asum[row0 + l15];
  const float av1 = asum[row0 + 16 + l15];
  unsigned mn0 = 0x7f800000u, mn1 = 0x7f800000u;
#pragma unroll
  for (int nt = 0; nt < NTIL; ++nt) {
    const f32x4 bv4 = *(const f32x4*)(bsum + col0 + nt * 128 + w * 16 + g * 4);
#pragma unroll
    for (int i = 0; i < 4; ++i) {
      const unsigned b0 = __float_as_uint(fmaf(-2.f, acc[0][nt][i], av0 + bv4[i]));
      const unsigned b1 = __float_as_uint(fmaf(-2.f, acc[1][nt][i], av1 + bv4[i]));
      mn0 = b0 < mn0 ? b0 : mn0;            // d>0: bit order == value order
      mn1 = b1 < mn1 ? b1 : mn1;
    }
  }
  {
    unsigned o = __shfl_xor(mn0, 16, 64); mn0 = o < mn0 ? o : mn0;
    o = __shfl_xor(mn0, 32, 64); mn0 = o < mn0 ? o : mn0;
    o = __shfl_xor(mn1, 16, 64); mn1 = o < mn1 ? o : mn1;
    o = __shfl_xor(mn1, 32, 64); mn1 = o < mn1 ? o : mn1;
    if (g == 0) {
      atomicMin(&rowMin32[l15], mn0);
      atomicMin(&rowMin32[16 + l15], mn1);
    }
  }
  __syncthreads();

  // two 16-row phases: dv -> swizzled LDS (Bs reuse) -> 4KB-run writeout
#pragma unroll
  for (int p = 0; p < 2; ++p) {
    const float avm = p ? av1 : av0;
    const float th = __uint_as_float(rowMin32[p * 16 + l15]) + REFINE_DELTA;
    const int rowG = row0 + p * 16 + l15;
#pragma unroll
    for (int nt = 0; nt < NTIL; ++nt) {
      const f32x4 bv4 = *(const f32x4*)(bsum + col0 + nt * 128 + w * 16 + g * 4);
      f32x4 dv4;
#pragma unroll
      for (int i = 0; i < 4; ++i) {
        dv4[i] = p ? fmaf(-2.f, acc[1][nt][i], avm + bv4[i])
                   : fmaf(-2.f, acc[0][nt][i], avm + bv4[i]);
        if (dv4[i] <= th) {
          const int pp = atomicAdd(&cnt[rowG], 1);
          if (pp < CAND_CAP)
            cand[(size_t)rowG * CAND_CAP + pp] =
                ((unsigned long long)__float_as_uint(dv4[i]) << 32) |
                (unsigned)(col0 + nt * 128 + w * 16 + g * 4 + i);
        }
      }
      const int chunk = nt * 32 + w * 4 + g;           // 16B chunk within row
      *(f32x4*)((char*)Bs + l15 * 4096 + ((chunk ^ (l15 & 7)) * 16)) = dv4;
    }
    __syncthreads();
    // writeout: 16 rows, 2 per wave; 4 x 1KB contiguous per row
#pragma unroll
    for (int rr = 0; rr < 2; ++rr) {
      const int rs = w * 2 + rr;                        // dump-buffer row slot
      float* dst = dmat + (size_t)(row0 + p * 16 + rs) * NE + col0;
#pragma unroll
      for (int i2 = 0; i2 < 4; ++i2) {
        const int c = i2 * 64 + lane;
        const f32x4 val = *(const f32x4*)((char*)Bs + rs * 4096 +
                                          ((c ^ (rs & 7)) * 16));
        __builtin_nontemporal_store(val, (f32x4*)(dst + c * 4));
      }
    }
    __syncthreads();                                    // before Bs reuse
  }
  if (tid < ROWS) pminv[(size_t)by * NROWS + row0 + tid] = rowMin32[tid];
}

// ---- combine panel minima -> final per-row min d value (bits) ----
__global__ void k_combine_dmin(const unsigned* __restrict__ pminv,
                               unsigned* __restrict__ gmin) {
  const int n = blockIdx.x * 256 + threadIdx.x;
  unsigned k = pminv[n];
#pragma unroll
  for (int p = 1; p < NPAN; ++p) {
    const unsigned o = pminv[(size_t)p * NROWS + n];
    k = o < k ? o : k;
  }
  gmin[n] = k;
}

// ---- exact np-replication argmin over collected candidates ----
__global__ __launch_bounds__(256) void k_exact(
    const float* __restrict__ dmat, const unsigned* __restrict__ gmin,
    const int* __restrict__ cnt, const unsigned long long* __restrict__ cand,
    const float* __restrict__ z, const float* __restrict__ emb,
    const float* __restrict__ asum,
    float* __restrict__ out_idx, int* __restrict__ idx_i) {
  __shared__ float zrow[4][CDIM];
  const int w = threadIdx.x >> 6, lane = threadIdx.x & 63;
  const int n = blockIdx.x * 4 + w;
  const int b = n >> 10, hw = n & 1023;

  const float* zb = z + (size_t)b * (CDIM * HWDIM) + hw;
#pragma unroll
  for (int j = 0; j < 4; ++j)
    zrow[w][lane * 4 + j] = zb[(size_t)(lane * 4 + j) * HWDIM];
  __syncthreads();

  const float A = asum[n];
  const float th = __uint_as_float(gmin[n]) + REFINE_DELTA;
  const float* zr = &zrow[w][lane * 4];
  const int c_ = cnt[n];
  unsigned long long best = ~0ull;

  if (c_ <= CAND_CAP) {
    for (int i = 0; i < c_; ++i) {
      const unsigned long long e = cand[(size_t)n * CAND_CAP + i];
      if (__uint_as_float((unsigned)(e >> 32)) > th) continue;  // vs FINAL min
      const int col = (int)(unsigned)(e & 0xffffffffull);
      const float4 ev = ((const float4*)(emb + (size_t)col * CDIM))[lane];
      double acc = (double)zr[0] * (double)ev.x;
      acc = fma((double)zr[1], (double)ev.y, acc);
      acc = fma((double)zr[2], (double)ev.z, acc);
      acc = fma((double)zr[3], (double)ev.w, acc);
#pragma unroll
      for (int s = 1; s < 64; s <<= 1) acc += __shfl_xor(acc, s, 64);
      const float C32 = (float)acc;
      const float D = A - 2.0f * C32;            // np: fl(A - 2C); 2C exact
      const unsigned long long key =
          ((unsigned long long)__float_as_uint(D) << 32) | (unsigned)col;
      if (key < best) best = key;
    }
  } else {
    // overflow fallback (rare): full row scan of stored d
    const float* drow = dmat + (size_t)n * NE;
    for (int i = 0; i < NE / 64; ++i) {
      const int colbase = i * 64;
      const float vv = drow[colbase + lane];
      unsigned long long mask = __ballot(vv <= th);
      while (mask) {
        const int bpos = (int)__builtin_ctzll(mask);
        mask &= mask - 1;
        const int col = colbase + bpos;
        const float4 ev = ((const float4*)(emb + (size_t)col * CDIM))[lane];
        double acc = (double)zr[0] * (double)ev.x;
        acc = fma((double)zr[1], (double)ev.y, acc);
        acc = fma((double)zr[2], (double)ev.z, acc);
        acc = fma((double)zr[3], (double)ev.w, acc);
#pragma unroll
        for (int s = 1; s < 64; s <<= 1) acc += __shfl_xor(acc, s, 64);
        const float C32 = (float)acc;
        const float D = A - 2.0f * C32;
        const unsigned long long key =
            ((unsigned long long)__float_as_uint(D) << 32) | (unsigned)col;
        if (key < best) best = key;
      }
    }
  }
  if (lane == 0) {
    const int bi = (int)(unsigned)(best & 0xffffffffull);
    idx_i[n] = bi;
    out_idx[n] = (float)bi;
  }
}

// ---- gather z_q, straight-through output, loss partial ----
__global__ void k_gather(const float* __restrict__ z, const float* __restrict__ emb,
                         const int* __restrict__ idx_i, float* __restrict__ zq_out,
                         float* __restrict__ loss_acc) {
  float part = 0.f;
  const unsigned stride = gridDim.x * 256u;
  for (unsigned i = blockIdx.x * 256u + threadIdx.x; i < 8388608u; i += stride) {
    const int hw = i & 1023;
    const int c  = (i >> 10) & 255;
    const int b  = i >> 18;
    const int n  = b * HWDIM + hw;
    const int e  = idx_i[n];
    const float zq = emb[(size_t)e * CDIM + c];
    const float zv = z[i];
    __builtin_nontemporal_store(zv + (zq - zv), &zq_out[i]);  // straight-through
    const float df = zq - zv;
    part = fmaf(df, df, part);
  }
#pragma unroll
  for (int s = 32; s; s >>= 1) part += __shfl_xor(part, s, 64);
  __shared__ float wsum[4];
  if ((threadIdx.x & 63) == 0) wsum[threadIdx.x >> 6] = part;
  __syncthreads();
  if (threadIdx.x == 0) atomicAdd(loss_acc, wsum[0] + wsum[1] + wsum[2] + wsum[3]);
}

__global__ void k_loss_final(const float* __restrict__ loss_acc, float* __restrict__ out_loss) {
  const float m = *loss_acc / 8388608.0f;
  *out_loss = m + 0.25f * m;
}

extern "C" void kernel_launch(void* const* d_in, const int* in_sizes, int n_in,
                              void* d_out, int out_size, void* d_ws, size_t ws_size,
                              hipStream_t stream) {
  const float* z   = (const float*)d_in[0];
  const float* emb = (const float*)d_in[1];
  float* out = (float*)d_out;
  char* ws = (char*)d_ws;

  __hip_bfloat16* zf   = (__hip_bfloat16*)(ws + WS_ZF);
  __hip_bfloat16* embb = (__hip_bfloat16*)(ws + WS_EMB);
  float* asum = (float*)(ws + WS_ASUM);
  float* bsum = (float*)(ws + WS_BSUM);
  unsigned* pminv = (unsigned*)(ws + WS_PMINV);
  unsigned* gmin = (unsigned*)(ws + WS_GMIN);
  int* cntp = (int*)(ws + WS_CNT);
  int* idxi = (int*)(ws + WS_IDX);
  float* lossacc = (float*)(ws + WS_LOSS);
  // candidate lists borrow the z_q output region (rewritten later by k_gather)
  unsigned long long* cand = (unsigned long long*)(out + OUT_ZQ);

  (void)hipMemsetAsync(ws + WS_CNT, 0, NROWS * 4, stream);
  (void)hipMemsetAsync(ws + WS_LOSS, 0, 4, stream);

  k_prep_zf<<<dim3(32, 8, 32), 256, 0, stream>>>(z, zf);
  k_prep_asum<<<128, 256, 0, stream>>>(z, asum);
  k_prep_emb<<<2048, 256, 0, stream>>>(emb, embb, bsum);
  k_gemm<<<dim3(1024, NPAN), 512, 0, stream>>>(zf, embb, asum, bsum,
                                               out + OUT_D, pminv, cntp, cand);
  k_combine_dmin<<<128, 256, 0, stream>>>(pminv, gmin);
  k_exact<<<8192, 256, 0, stream>>>(out + OUT_D, gmin, cntp, cand, z, emb, asum,
                                    out + OUT_IDX, idxi);
  k_gather<<<2048, 256, 0, stream>>>(z, emb, idxi, out + OUT_ZQ, lossacc);
  k_loss_final<<<1, 1, 0, stream>>>(lossacc, out + OUT_LOSS);
}